// Round 11
// baseline (858.288 us; speedup 1.0000x reference)
//
#include <hip/hip_runtime.h>
#include <stdint.h>

typedef unsigned short ushort_t;
typedef __bf16 bf16x8 __attribute__((ext_vector_type(8)));
typedef float f32x4 __attribute__((ext_vector_type(4)));

#define TOTAL_HW 20267
#define PTOT 21267          // padded pyramid pixels per batch

// reg-head fused channel mapping (26 channels -> 6 tensors in d_out), f32 element offsets
__constant__ int d_RB[26] = {3242720,3242720,3242720,3242720, 3404856, 3445390,3445390,3445390,
                             3566992, 3607526,3607526,3607526,3607526,3607526,3607526,3607526,3607526,
                             3607526,3607526,3607526,3607526,3607526,3607526,3607526,3607526, 4256070};
__constant__ int d_RM[26] = {4,4,4,4, 1, 3,3,3, 1, 16,16,16,16,16,16,16,16,16,16,16,16,16,16,16,16, 1};
__constant__ int d_RC[26] = {0,1,2,3, 0, 0,1,2, 0, 0,1,2,3,4,5,6,7,8,9,10,11,12,13,14,15, 0};

// level geometry
__constant__ int F_TC[6]   = {0,238,298,314,318,320};
__constant__ int F_TL[5]   = {119,30,8,2,1};
__constant__ int F_W[5]    = {152,76,38,19,10};
__constant__ int F_HW[5]   = {15200,3800,950,247,70};
__constant__ int F_PB[5]   = {0,15708,19764,20844,21159};   // padded pixel base within batch
__constant__ int F_LOFF[5] = {0,15200,19000,19950,20197};
__constant__ int F_PC[6]   = {0,508,764,894,962,1000};      // pad-pixel cumsum
__constant__ int F_H[5]    = {100,50,25,13,7};

__device__ __forceinline__ ushort_t f2bf(float f) {
    union { float f; uint32_t i; } x; x.f = f;
    uint32_t r = x.i + 0x7fffu + ((x.i >> 16) & 1u);   // RNE
    return (ushort_t)(r >> 16);
}
__device__ __forceinline__ float bf2f(ushort_t u) {
    union { uint32_t i; float f; } x; x.i = ((uint32_t)u) << 16; return x.f;
}
__device__ __forceinline__ void gld16(const ushort_t* g, ushort_t* lds) {
    __builtin_amdgcn_global_load_lds((const __attribute__((address_space(1))) void*)g,
                                     (__attribute__((address_space(3))) void*)lds, 16, 0, 0);
}

// ================= unified weight prep (tower + cls + reg) + Stats zero =================
// Weights stored FRAGMENT-MAJOR: per (tap t, q, kh, s8): [oc][8 elems], so a wave's MFMA
// B-fragment (lane ln -> B[rB][kh*32+(ln>>4)*8+e]) is a coalesced 16B load per lane.
// ic = q*64 + kh*32 + s8*8 + e. Per-t stride unchanged (65536 tower / 32768 head).
__global__ __launch_bounds__(256) void wprep_k(
    const float* __restrict__ cw, const float* __restrict__ rw,
    const float* __restrict__ cls_out_w,
    const float* bbox_w, const float* ctr_w, const float* dim_w,
    const float* ori_w,  const float* kp_w,  const float* depth_w,
    const float* bbox_b, const float* ctr_b, const float* dim_b,
    const float* ori_b,  const float* kp_b,  const float* depth_b,
    ushort_t* __restrict__ TowerWtAll, ushort_t* __restrict__ WtCls,
    ushort_t* __restrict__ WtReg, float* __restrict__ RegBias,
    float* __restrict__ Stats)
{
    int bid = blockIdx.x;
    if (bid < 2048) {                       // tower weights: 524288 ids
        int id = bid * 256 + threadIdx.x;
        int g = id >> 16;                   // tw*4 + L, 0..7
        int oc = (id >> 8) & 255, ic = id & 255;
        const float* base = (g >= 4) ? rw : cw;
        int L = g & 3;
        const float* s = base + (size_t)L * 589824 + (size_t)(oc * 256 + ic) * 9;
        int q = ic >> 6, kh = (ic >> 5) & 1, s8 = (ic >> 3) & 3, e = ic & 7;
        ushort_t* d = TowerWtAll + (size_t)g * 589824 + (((q * 2 + kh) * 4 + s8) * 2048) + oc * 8 + e;
        #pragma unroll
        for (int t = 0; t < 9; t++) d[t * 65536] = f2bf(s[t]);
    } else if (bid < 2176) {                // cls head: 32768 ids
        int id = (bid - 2048) * 256 + threadIdx.x;
        int oc = id >> 8, ic = id & 255;
        int q = ic >> 6, kh = (ic >> 5) & 1, s8 = (ic >> 3) & 3, e = ic & 7;
        ushort_t* d = WtCls + (((q * 2 + kh) * 4 + s8) * 1024) + oc * 8 + e;
        if (oc < 80) {
            const float* s = cls_out_w + (size_t)(oc * 256 + ic) * 9;
            #pragma unroll
            for (int t = 0; t < 9; t++) d[t * 32768] = f2bf(s[t]);
        } else {
            #pragma unroll
            for (int t = 0; t < 9; t++) d[t * 32768] = 0;
        }
    } else {                                // reg head: 32768 ids (+ stats zero)
        int id = (bid - 2176) * 256 + threadIdx.x;
        if (id < 5120) Stats[id] = 0.f;     // 20480 B of stats
        int oc = id >> 8, ic = id & 255;
        int q = ic >> 6, kh = (ic >> 5) & 1, s8 = (ic >> 3) & 3, e = ic & 7;
        ushort_t* d = WtReg + (((q * 2 + kh) * 4 + s8) * 1024) + oc * 8 + e;
        if (oc < 26) {
            const float* s; int c;
            if (oc < 4)       { s = bbox_w;  c = oc; }
            else if (oc < 5)  { s = ctr_w;   c = 0; }
            else if (oc < 8)  { s = dim_w;   c = oc - 5; }
            else if (oc < 9)  { s = ori_w;   c = 0; }
            else if (oc < 25) { s = kp_w;    c = oc - 9; }
            else              { s = depth_w; c = 0; }
            const float* sp = s + (size_t)(c * 256 + ic) * 9;
            #pragma unroll
            for (int t = 0; t < 9; t++) d[t * 32768] = f2bf(sp[t]);
        } else {
            #pragma unroll
            for (int t = 0; t < 9; t++) d[t * 32768] = 0;
        }
        if (id < 26) {
            const float* b; int c;
            if (id < 4)       { b = bbox_b;  c = id; }
            else if (id < 5)  { b = ctr_b;   c = 0; }
            else if (id < 8)  { b = dim_b;   c = id - 5; }
            else if (id < 9)  { b = ori_b;   c = 0; }
            else if (id < 25) { b = kp_b;    c = id - 9; }
            else              { b = depth_b; c = 0; }
            RegBias[id] = b[c];
        }
    }
}

// ================= pack all levels (f32 NCHW -> padded bf16 NHWC) + border zeroing =================
__global__ __launch_bounds__(256) void packF_k(
    const float* f0, const float* f1, const float* f2,
    const float* f3, const float* f4, ushort_t* __restrict__ S,
    ushort_t* __restrict__ pb1, ushort_t* __restrict__ pb2, ushort_t* __restrict__ pb3)
{
    int bid = blockIdx.x;
    if (bid >= 2552) {                      // pad path: zero borders of 4 buffers (1000 blocks)
        int u = (bid - 2552) * 256 + threadIdx.x;     // 256000 total
        if (u >= 256000) return;
        int chunk = u & 31; u >>= 5;
        int buf = u & 3; u >>= 2;
        int n = (u >= 1000) ? 1 : 0; int pidx = u - n * 1000;
        int l = 0;
        #pragma unroll
        for (int i = 1; i < 5; i++) if (pidx >= F_PC[i]) l = i;
        int q = pidx - F_PC[l];
        int W = F_W[l], H = F_H[l], Wp = W + 2;
        int py, px;
        if (q < Wp) { py = 0; px = q; }
        else if (q < 2 * Wp) { py = H + 1; px = q - Wp; }
        else { int q2 = q - 2 * Wp; py = 1 + (q2 >> 1); px = (q2 & 1) ? (Wp - 1) : 0; }
        ushort_t* base = S;
        if (buf == 1) base = pb1; else if (buf == 2) base = pb2; else if (buf == 3) base = pb3;
        *(uint4*)(base + ((size_t)n * PTOT + F_PB[l] + py * Wp + px) * 256 + chunk * 8) = uint4{0u,0u,0u,0u};
        return;
    }
    __shared__ ushort_t tile[64][65];
    const int PCUM[6] = {0, 1904, 2384, 2504, 2536, 2552};
    const int PT[5]   = {238, 60, 15, 4, 2};
    int l = 0;
    #pragma unroll
    for (int i = 1; i < 5; i++) if (bid >= PCUM[i]) l = i;
    int r = bid - PCUM[l];
    int per_n = PT[l] * 4;
    int n = (r >= per_n) ? 1 : 0; r -= n * per_n;
    int pb = r >> 2, cb = r & 3;
    const float* fs = f0;
    if (l == 1) fs = f1; else if (l == 2) fs = f2; else if (l == 3) fs = f3; else if (l == 4) fs = f4;
    int HW = F_HW[l], W = F_W[l], Wp = W + 2;
    int p0 = pb * 64, c0 = cb * 64;
    int t = threadIdx.x;
    bool full = (p0 + 64 <= HW);
    if (full && l <= 1) {
        #pragma unroll
        for (int i = 0; i < 4; i++) {
            int idx = i * 256 + t; int cl = idx >> 4, pw = idx & 15;
            const float* rp = fs + (size_t)(n * 256 + c0 + cl) * HW + p0 + pw * 4;
            float4 v = *(const float4*)rp;
            tile[cl][pw * 4 + 0] = f2bf(v.x);
            tile[cl][pw * 4 + 1] = f2bf(v.y);
            tile[cl][pw * 4 + 2] = f2bf(v.z);
            tile[cl][pw * 4 + 3] = f2bf(v.w);
        }
    } else if (full && (l == 2 || l == 4)) {
        #pragma unroll
        for (int i = 0; i < 8; i++) {
            int idx = i * 256 + t; int cl = idx >> 5, pw = idx & 31;
            const float* rp = fs + (size_t)(n * 256 + c0 + cl) * HW + p0 + pw * 2;
            float2 v = *(const float2*)rp;
            tile[cl][pw * 2 + 0] = f2bf(v.x);
            tile[cl][pw * 2 + 1] = f2bf(v.y);
        }
    } else {
        #pragma unroll
        for (int i = 0; i < 16; i++) {
            int idx = i * 256 + t; int cl = idx >> 6, pl = idx & 63;
            int p = p0 + pl; ushort_t v = 0;
            if (p < HW) v = f2bf(fs[(size_t)(n * 256 + c0 + cl) * HW + p]);
            tile[cl][pl] = v;
        }
    }
    __syncthreads();
    ushort_t* ob = S + ((size_t)n * PTOT + F_PB[l]) * 256;
    #pragma unroll
    for (int i = 0; i < 16; i++) {
        int idx = i * 256 + t; int pl = idx >> 6, cl = idx & 63;
        int p = p0 + pl;
        if (p < HW) {
            int y = p / W, x = p - y * W;
            ob[((y + 1) * Wp + (x + 1)) * 256 + c0 + cl] = tile[cl][pl];
        }
    }
}

// ================= tower conv: BK=64, K-split pairs, A via LDS, B direct global->reg ========
// 8 waves = (wr,wc,kh) 2x2x2. B-fragments loaded straight from the fragment-major weight
// tensor (L2-resident, coalesced) -> LDS port only carries A (reads halved, writes -33%).
__global__ __launch_bounds__(512, 4) void convT_k(
    const ushort_t* __restrict__ srcC, const ushort_t* __restrict__ srcR,
    ushort_t* __restrict__ dstC, ushort_t* __restrict__ dstR,
    const ushort_t* __restrict__ wtAll,
    const float* __restrict__ biasC, const float* __restrict__ biasR,
    float* __restrict__ stats, int L)
{
    __shared__ __align__(16) ushort_t SH[32768];   // A: [b*8192 + kh*4096 + row*32 + c*8]; merge reuses all

    int gid = blockIdx.x;                       // 0..1279
    int xcd = gid & 7, idx = gid >> 3;          // idx 0..159
    int bid = xcd * 40 + (idx >> 2);            // tile id 0..319 (span-local to XCD)
    int oc0 = (idx & 1) * 128;
    int tw = (idx >> 1) & 1;

    const ushort_t* src = tw ? srcR : srcC;
    ushort_t* dst = tw ? dstR : dstC;
    const ushort_t* wt = wtAll + (size_t)(tw * 4 + L) * 589824;
    const float* bias = (tw ? biasR : biasC) + L * 256;

    int l = 0;
    #pragma unroll
    for (int i = 1; i < 5; i++) if (bid >= F_TC[i]) l = i;
    int r = bid - F_TC[l];
    int tl = F_TL[l];
    int n = (r >= tl) ? 1 : 0; int tile = r - n * tl;
    int W = F_W[l], HW = F_HW[l], Wp = W + 2;
    int px0 = tile * 128;
    const ushort_t* sbase = src + ((size_t)n * PTOT + F_PB[l]) * 256;
    ushort_t* obase = dst + ((size_t)n * PTOT + F_PB[l]) * 256;

    int tid = threadIdx.x, wv = tid >> 6, ln = tid & 63;   // wv 0..7
    int wr = (wv >> 1) & 1, wc = wv & 1, kh = wv >> 2;     // 2M x 2N x 2K-halves

    int aoff;
    {
        int rloc = wv * 16 + (ln >> 2);
        int p = px0 + rloc; if (p > HW - 1) p = HW - 1;
        int y = p / W, x = p - y * W;
        int c = ((ln & 3) - (rloc >> 1)) & 3;       // global sub-chunk for this LDS slot
        aoff = ((y + 1) * Wp + (x + 1)) * 256 + c * 8;
    }
    // per-lane offset within a (t,q,kh) fragment block: s8 = ln>>4, then [oc][8]
    int fragoff = (ln >> 4) * 2048;

    auto stageA = [&](int it, int b) {
        int tp = it >> 2, q = it & 3;
        int ky = tp / 3, kx = tp - ky * 3;
        int tapo = ((ky - 1) * Wp + (kx - 1)) * 256 + (q << 6);
        gld16(sbase + aoff + tapo,      &SH[b * 8192 + wv * 512]);
        gld16(sbase + aoff + tapo + 32, &SH[b * 8192 + 4096 + wv * 512]);
    };

    f32x4 acc[4][4];
    #pragma unroll
    for (int mi = 0; mi < 4; mi++)
        #pragma unroll
        for (int ni = 0; ni < 4; ni++) acc[mi][ni] = f32x4{0.f, 0.f, 0.f, 0.f};

    stageA(0, 0);

    #pragma unroll 2
    for (int it = 0; it < 36; ++it) {
        asm volatile("s_waitcnt vmcnt(0) lgkmcnt(0)\n\ts_barrier" ::: "memory");
        int tp = it >> 2, q = it & 3;
        // B fragments: direct, coalesced (16-lane contiguous 256B segments), L2-hot
        const ushort_t* wB = wt + (size_t)(((tp * 4 + q) * 2 + kh) * 4) * 2048 + fragoff;
        bf16x8 bg[4];
        #pragma unroll
        for (int ni = 0; ni < 4; ni++)
            bg[ni] = *(const bf16x8*)&wB[(oc0 + wc * 64 + ni * 16 + (ln & 15)) * 8];
        if (it + 1 < 36) stageA(it + 1, (it + 1) & 1);
        int b = it & 1;
        bf16x8 af[4];
        #pragma unroll
        for (int mi = 0; mi < 4; mi++) {
            int rA = wr * 64 + mi * 16 + (ln & 15);
            int ch = ((ln >> 4) + (rA >> 1)) & 3;
            af[mi] = *(const bf16x8*)&SH[b * 8192 + kh * 4096 + rA * 32 + ch * 8];
        }
        __builtin_amdgcn_s_setprio(1);
        #pragma unroll
        for (int mi = 0; mi < 4; mi++)
            #pragma unroll
            for (int ni = 0; ni < 4; ni++)
                acc[mi][ni] = __builtin_amdgcn_mfma_f32_16x16x32_bf16(af[mi], bg[ni], acc[mi][ni], 0, 0, 0);
        __builtin_amdgcn_s_setprio(0);
    }

    // ---- K-split merge: pair (wv, wv^4). STATIC indices only (rule #20). ----
    __syncthreads();
    f32x4* F4 = (f32x4*)SH;
    int prt = wv ^ 4;
    if (kh == 0) {
        #pragma unroll
        for (int mi = 0; mi < 4; mi++) {
            F4[wv * 512 + ln * 8 + ((mi * 2 + 0) ^ (ln & 7))] = acc[mi][2];
            F4[wv * 512 + ln * 8 + ((mi * 2 + 1) ^ (ln & 7))] = acc[mi][3];
        }
    } else {
        #pragma unroll
        for (int mi = 0; mi < 4; mi++) {
            F4[wv * 512 + ln * 8 + ((mi * 2 + 0) ^ (ln & 7))] = acc[mi][0];
            F4[wv * 512 + ln * 8 + ((mi * 2 + 1) ^ (ln & 7))] = acc[mi][1];
        }
    }
    __syncthreads();
    f32x4 eacc[4][2];
    if (kh == 0) {
        #pragma unroll
        for (int mi = 0; mi < 4; mi++) {
            eacc[mi][0] = acc[mi][0] + F4[prt * 512 + ln * 8 + ((mi * 2 + 0) ^ (ln & 7))];
            eacc[mi][1] = acc[mi][1] + F4[prt * 512 + ln * 8 + ((mi * 2 + 1) ^ (ln & 7))];
        }
    } else {
        #pragma unroll
        for (int mi = 0; mi < 4; mi++) {
            eacc[mi][0] = acc[mi][2] + F4[prt * 512 + ln * 8 + ((mi * 2 + 0) ^ (ln & 7))];
            eacc[mi][1] = acc[mi][3] + F4[prt * 512 + ln * 8 + ((mi * 2 + 1) ^ (ln & 7))];
        }
    }

    // epilogue: this wave finalizes ni = kh*2 + {0,1}
    #pragma unroll
    for (int h = 0; h < 2; h++) {
        int oc = oc0 + wc * 64 + (kh * 2 + h) * 16 + (ln & 15);
        float bv = bias[oc];
        float s = 0.f, q = 0.f;
        #pragma unroll
        for (int mi = 0; mi < 4; mi++) {
            int pb = px0 + wr * 64 + mi * 16 + ((ln >> 4) << 2);
            if (pb < HW) {
                int y = pb / W, x = pb - y * W;
                #pragma unroll
                for (int rr2 = 0; rr2 < 4; rr2++) {
                    int p = pb + rr2;
                    if (p < HW) {
                        float v = eacc[mi][h][rr2] + bv;
                        obase[((y + 1) * Wp + (x + 1)) * 256 + oc] = f2bf(v);
                        s += v; q += v * v;
                    }
                    x++; if (x == W) { x = 0; y++; }
                }
            }
        }
        s += __shfl_xor(s, 16, 64); q += __shfl_xor(q, 16, 64);
        s += __shfl_xor(s, 32, 64); q += __shfl_xor(q, 32, 64);
        s += __shfl_xor(s, 1, 64);  q += __shfl_xor(q, 1, 64);
        s += __shfl_xor(s, 2, 64);  q += __shfl_xor(q, 2, 64);
        s += __shfl_xor(s, 4, 64);  q += __shfl_xor(q, 4, 64);
        if (ln == 0 || ln == 8) {
            int g = (oc0 + wc * 64 + (kh * 2 + h) * 16 + (ln & 8)) >> 3;
            float* st = stats + (size_t)((tw * 4 + L) * 5 + l) * 128 + (n * 32 + g) * 2;
            atomicAdd(st, s); atomicAdd(st + 1, q);
        }
    }
}

// ================= head conv: BK=64, K-split pairs, B direct->reg; mode-1 dead-wave skip ==========
__global__ __launch_bounds__(512, 4) void convH_k(
    const ushort_t* __restrict__ srcC, const ushort_t* __restrict__ srcR,
    const ushort_t* __restrict__ wtC, const ushort_t* __restrict__ wtR,
    const float* __restrict__ biasC, const float* __restrict__ biasR,
    float* __restrict__ outF)
{
    __shared__ __align__(16) ushort_t SH[32768];

    int gid = blockIdx.x;                      // 0..639
    int xcd = gid & 7, idx = gid >> 3;         // idx 0..79
    int bid = xcd * 40 + (idx >> 1);           // tile 0..319
    int mode = idx & 1;

    const ushort_t* src = mode ? srcR : srcC;
    const ushort_t* wt  = mode ? wtR  : wtC;
    const float* bias   = mode ? biasR : biasC;

    int l = 0;
    #pragma unroll
    for (int i = 1; i < 5; i++) if (bid >= F_TC[i]) l = i;
    int r = bid - F_TC[l];
    int tl = F_TL[l];
    int n = (r >= tl) ? 1 : 0; int tile = r - n * tl;
    int W = F_W[l], HW = F_HW[l], Wp = W + 2;
    int px0 = tile * 128;
    const ushort_t* sbase = src + ((size_t)n * PTOT + F_PB[l]) * 256;

    int tid = threadIdx.x, wv = tid >> 6, ln = tid & 63;
    int wr = (wv >> 1) & 1, wc = wv & 1, kh = wv >> 2;
    bool active = (mode == 0) || (wc == 0);   // mode1: only oc<26 valid (all in wc==0)

    int aoff;
    {
        int rloc = wv * 16 + (ln >> 2);
        int p = px0 + rloc; if (p > HW - 1) p = HW - 1;
        int y = p / W, x = p - y * W;
        int c = ((ln & 3) - (rloc >> 1)) & 3;
        aoff = ((y + 1) * Wp + (x + 1)) * 256 + c * 8;
    }
    int fragoff = (ln >> 4) * 1024;

    auto stageA = [&](int it, int b) {
        int tp = it >> 2, q = it & 3;
        int ky = tp / 3, kx = tp - ky * 3;
        int tapo = ((ky - 1) * Wp + (kx - 1)) * 256 + (q << 6);
        gld16(sbase + aoff + tapo,      &SH[b * 8192 + wv * 512]);
        gld16(sbase + aoff + tapo + 32, &SH[b * 8192 + 4096 + wv * 512]);
    };

    f32x4 acc[4][4];
    #pragma unroll
    for (int mi = 0; mi < 4; mi++)
        #pragma unroll
        for (int ni = 0; ni < 4; ni++) acc[mi][ni] = f32x4{0.f, 0.f, 0.f, 0.f};

    stageA(0, 0);

    #pragma unroll 2
    for (int it = 0; it < 36; ++it) {
        asm volatile("s_waitcnt vmcnt(0) lgkmcnt(0)\n\ts_barrier" ::: "memory");
        int tp = it >> 2, q = it & 3;
        if (it + 1 < 36) stageA(it + 1, (it + 1) & 1);
        int b = it & 1;
        if (active) {
            const ushort_t* wB = wt + (size_t)(((tp * 4 + q) * 2 + kh) * 4) * 1024 + fragoff;
            bf16x8 bg[4];
            #pragma unroll
            for (int ni = 0; ni < 4; ni++)
                bg[ni] = *(const bf16x8*)&wB[(wc * 64 + ni * 16 + (ln & 15)) * 8];
            bf16x8 af[4];
            #pragma unroll
            for (int mi = 0; mi < 4; mi++) {
                int rA = wr * 64 + mi * 16 + (ln & 15);
                int ch = ((ln >> 4) + (rA >> 1)) & 3;
                af[mi] = *(const bf16x8*)&SH[b * 8192 + kh * 4096 + rA * 32 + ch * 8];
            }
            __builtin_amdgcn_s_setprio(1);
            #pragma unroll
            for (int mi = 0; mi < 4; mi++)
                #pragma unroll
                for (int ni = 0; ni < 4; ni++)
                    acc[mi][ni] = __builtin_amdgcn_mfma_f32_16x16x32_bf16(af[mi], bg[ni], acc[mi][ni], 0, 0, 0);
            __builtin_amdgcn_s_setprio(0);
        }
    }

    __syncthreads();
    f32x4* F4 = (f32x4*)SH;
    int prt = wv ^ 4;
    if (active) {
        if (kh == 0) {
            #pragma unroll
            for (int mi = 0; mi < 4; mi++) {
                F4[wv * 512 + ln * 8 + ((mi * 2 + 0) ^ (ln & 7))] = acc[mi][2];
                F4[wv * 512 + ln * 8 + ((mi * 2 + 1) ^ (ln & 7))] = acc[mi][3];
            }
        } else {
            #pragma unroll
            for (int mi = 0; mi < 4; mi++) {
                F4[wv * 512 + ln * 8 + ((mi * 2 + 0) ^ (ln & 7))] = acc[mi][0];
                F4[wv * 512 + ln * 8 + ((mi * 2 + 1) ^ (ln & 7))] = acc[mi][1];
            }
        }
    }
    __syncthreads();
    f32x4 eacc[4][2];
    if (kh == 0) {
        #pragma unroll
        for (int mi = 0; mi < 4; mi++) {
            eacc[mi][0] = acc[mi][0] + F4[prt * 512 + ln * 8 + ((mi * 2 + 0) ^ (ln & 7))];
            eacc[mi][1] = acc[mi][1] + F4[prt * 512 + ln * 8 + ((mi * 2 + 1) ^ (ln & 7))];
        }
    } else {
        #pragma unroll
        for (int mi = 0; mi < 4; mi++) {
            eacc[mi][0] = acc[mi][2] + F4[prt * 512 + ln * 8 + ((mi * 2 + 0) ^ (ln & 7))];
            eacc[mi][1] = acc[mi][3] + F4[prt * 512 + ln * 8 + ((mi * 2 + 1) ^ (ln & 7))];
        }
    }

    #pragma unroll
    for (int h = 0; h < 2; h++) {
        int oc = wc * 64 + (kh * 2 + h) * 16 + (ln & 15);
        bool valid = mode ? (oc < 26) : (oc < 80);
        if (valid) {
            float bv = bias[oc];
            int rb = 0, rm = 80, rc = oc; bool rl = false;
            if (mode) { rb = d_RB[oc]; rm = d_RM[oc]; rc = d_RC[oc]; rl = (oc < 4); }
            #pragma unroll
            for (int mi = 0; mi < 4; mi++) {
                int pb = px0 + wr * 64 + mi * 16 + ((ln >> 4) << 2);
                #pragma unroll
                for (int rr2 = 0; rr2 < 4; rr2++) {
                    int p = pb + rr2;
                    if (p < HW) {
                        float v = eacc[mi][h][rr2] + bv;
                        if (rl) v = fmaxf(v, 0.f);
                        int pg = n * TOTAL_HW + F_LOFF[l] + p;
                        outF[rb + (size_t)pg * rm + rc] = v;
                    }
                }
            }
        }
    }
}

// ================= merged GN finalize+affine+relu (both towers, all levels) =================
__global__ __launch_bounds__(256) void normF_k(
    ushort_t* __restrict__ bufC, ushort_t* __restrict__ bufR,
    const float* __restrict__ stats,
    const float* __restrict__ gwC, const float* __restrict__ gwR,
    const float* __restrict__ gbC, const float* __restrict__ gbR, int L)
{
    int u = blockIdx.x * 256 + threadIdx.x;
    if (u >= 2594176) return;                 // 2tw * 2n * 20267 * 32
    int tw = (u >= 1297088) ? 1 : 0; u -= tw * 1297088;
    int n = (u >= 648544) ? 1 : 0; u -= n * 648544;
    int cp = u >> 5, g = u & 31;
    int l = 0;
    #pragma unroll
    for (int i = 1; i < 5; i++) if (cp >= F_LOFF[i]) l = i;
    int p = cp - F_LOFF[l];
    int W = F_W[l], HW = F_HW[l];
    int y = p / W, x = p - y * W;
    const float* st = stats + (size_t)((tw * 4 + L) * 5 + l) * 128 + (n * 32 + g) * 2;
    float cnt = 8.0f * (float)HW;
    float mean = st[0] / cnt;
    float var = st[1] / cnt - mean * mean;
    float inv = rsqrtf(fmaxf(var, 0.f) + 1e-5f);
    const float* gw = (tw ? gwR : gwC) + L * 256 + g * 8;
    const float* gb = (tw ? gbR : gbC) + L * 256 + g * 8;
    ushort_t* buf = tw ? bufR : bufC;
    ushort_t* ptr = buf + (((size_t)n * PTOT + F_PB[l]) + (y + 1) * (W + 2) + (x + 1)) * 256 + g * 8;
    uint4 din = *(const uint4*)ptr;
    uint4 dout;
    const ushort_t* xi = (const ushort_t*)&din;
    ushort_t* oi = (ushort_t*)&dout;
    #pragma unroll
    for (int i = 0; i < 8; i++) {
        float v = (bf2f(xi[i]) - mean) * inv * gw[i] + gb[i];
        oi[i] = f2bf(fmaxf(v, 0.f));
    }
    *(uint4*)ptr = dout;
}

// ---------------- ws layout (bytes) ----------------
// Stats 0..20,480 | RegBias 20,480..20,608 | TowerWtAll 20,608..9,457,792
// WtCls 9,457,792..10,047,616 | WtReg 10,047,616..10,637,440
// S 10,637,440 | Ac 32,414,848 | Ar 54,192,256 | Br 75,969,664 | end 97,747,072

extern "C" void kernel_launch(void* const* d_in, const int* in_sizes, int n_in,
                              void* d_out, int out_size, void* d_ws, size_t ws_size,
                              hipStream_t stream) {
    const float* feats[5] = {(const float*)d_in[0], (const float*)d_in[1],
                             (const float*)d_in[2], (const float*)d_in[3],
                             (const float*)d_in[4]};
    const float* cls_conv_w = (const float*)d_in[5];
    const float* cls_conv_b = (const float*)d_in[6];
    const float* cls_gn_w   = (const float*)d_in[7];
    const float* cls_gn_b   = (const float*)d_in[8];
    const float* cls_out_w  = (const float*)d_in[9];
    const float* cls_out_b  = (const float*)d_in[10];
    const float* reg_conv_w = (const float*)d_in[11];
    const float* reg_conv_b = (const float*)d_in[12];
    const float* reg_gn_w   = (const float*)d_in[13];
    const float* reg_gn_b   = (const float*)d_in[14];

    char* wsb = (char*)d_ws;
    float* Stats     = (float*)wsb;
    float* RegBias   = (float*)(wsb + 20480);
    ushort_t* TowerWtAll = (ushort_t*)(wsb + 20608);
    ushort_t* WtCls  = (ushort_t*)(wsb + 9457792);
    ushort_t* WtReg  = (ushort_t*)(wsb + 10047616);
    ushort_t* S  = (ushort_t*)(wsb + 10637440);
    ushort_t* Ac = (ushort_t*)(wsb + 32414848);
    ushort_t* Ar = (ushort_t*)(wsb + 54192256);
    ushort_t* Br = (ushort_t*)(wsb + 75969664);
    float* outf  = (float*)d_out;

    wprep_k<<<2304, 256, 0, stream>>>(
        cls_conv_w, reg_conv_w, cls_out_w,
        (const float*)d_in[15], (const float*)d_in[17], (const float*)d_in[19],
        (const float*)d_in[21], (const float*)d_in[23], (const float*)d_in[25],
        (const float*)d_in[16], (const float*)d_in[18], (const float*)d_in[20],
        (const float*)d_in[22], (const float*)d_in[24], (const float*)d_in[26],
        TowerWtAll, WtCls, WtReg, RegBias, Stats);

    packF_k<<<3552, 256, 0, stream>>>(feats[0], feats[1], feats[2], feats[3], feats[4],
                                      S, Ac, Ar, Br);

    ushort_t* sc[4] = {S,  Ac, S,  Ac};
    ushort_t* dc[4] = {Ac, S,  Ac, S };
    ushort_t* sr[4] = {S,  Ar, Br, Ar};
    ushort_t* dr[4] = {Ar, Br, Ar, Br};
    for (int L = 0; L < 4; L++) {
        convT_k<<<1280, 512, 0, stream>>>(
            sc[L], sr[L], dc[L], dr[L], TowerWtAll, cls_conv_b, reg_conv_b, Stats, L);
        normF_k<<<10134, 256, 0, stream>>>(
            dc[L], dr[L], Stats, cls_gn_w, reg_gn_w, cls_gn_b, reg_gn_b, L);
    }
    convH_k<<<640, 512, 0, stream>>>(S, Br, WtCls, WtReg, cls_out_b, RegBias, outf);
}

// Round 12
// 767.183 us; speedup vs baseline: 1.1188x; 1.1188x over previous
//
#include <hip/hip_runtime.h>
#include <stdint.h>

typedef unsigned short ushort_t;
typedef __bf16 bf16x8 __attribute__((ext_vector_type(8)));
typedef float f32x4 __attribute__((ext_vector_type(4)));

#define TOTAL_HW 20267
#define PTOT 21267          // padded pyramid pixels per batch

// reg-head fused channel mapping (26 channels -> 6 tensors in d_out), f32 element offsets
__constant__ int d_RB[26] = {3242720,3242720,3242720,3242720, 3404856, 3445390,3445390,3445390,
                             3566992, 3607526,3607526,3607526,3607526,3607526,3607526,3607526,3607526,
                             3607526,3607526,3607526,3607526,3607526,3607526,3607526,3607526, 4256070};
__constant__ int d_RM[26] = {4,4,4,4, 1, 3,3,3, 1, 16,16,16,16,16,16,16,16,16,16,16,16,16,16,16,16, 1};
__constant__ int d_RC[26] = {0,1,2,3, 0, 0,1,2, 0, 0,1,2,3,4,5,6,7,8,9,10,11,12,13,14,15, 0};

// level geometry
__constant__ int F_TC[6]   = {0,238,298,314,318,320};
__constant__ int F_TL[5]   = {119,30,8,2,1};
__constant__ int F_W[5]    = {152,76,38,19,10};
__constant__ int F_HW[5]   = {15200,3800,950,247,70};
__constant__ int F_PB[5]   = {0,15708,19764,20844,21159};   // padded pixel base within batch
__constant__ int F_LOFF[5] = {0,15200,19000,19950,20197};
__constant__ int F_PC[6]   = {0,508,764,894,962,1000};      // pad-pixel cumsum
__constant__ int F_H[5]    = {100,50,25,13,7};

__device__ __forceinline__ ushort_t f2bf(float f) {
    union { float f; uint32_t i; } x; x.f = f;
    uint32_t r = x.i + 0x7fffu + ((x.i >> 16) & 1u);   // RNE
    return (ushort_t)(r >> 16);
}
__device__ __forceinline__ float bf2f(ushort_t u) {
    union { uint32_t i; float f; } x; x.i = ((uint32_t)u) << 16; return x.f;
}
__device__ __forceinline__ void gld16(const ushort_t* g, ushort_t* lds) {
    __builtin_amdgcn_global_load_lds((const __attribute__((address_space(1))) void*)g,
                                     (__attribute__((address_space(3))) void*)lds, 16, 0, 0);
}

// ================= unified weight prep (tower + cls + reg) + Stats zero =================
// Weights FRAGMENT-MAJOR: per (tap t, q, kh, s8): [oc][8 elems] -> a wave's MFMA B-fragment
// is a coalesced 16B/lane load. ic = q*64 + kh*32 + s8*8 + e.
__global__ __launch_bounds__(256) void wprep_k(
    const float* __restrict__ cw, const float* __restrict__ rw,
    const float* __restrict__ cls_out_w,
    const float* bbox_w, const float* ctr_w, const float* dim_w,
    const float* ori_w,  const float* kp_w,  const float* depth_w,
    const float* bbox_b, const float* ctr_b, const float* dim_b,
    const float* ori_b,  const float* kp_b,  const float* depth_b,
    ushort_t* __restrict__ TowerWtAll, ushort_t* __restrict__ WtCls,
    ushort_t* __restrict__ WtReg, float* __restrict__ RegBias,
    float* __restrict__ Stats)
{
    int bid = blockIdx.x;
    if (bid < 2048) {                       // tower weights: 524288 ids
        int id = bid * 256 + threadIdx.x;
        int g = id >> 16;                   // tw*4 + L, 0..7
        int oc = (id >> 8) & 255, ic = id & 255;
        const float* base = (g >= 4) ? rw : cw;
        int L = g & 3;
        const float* s = base + (size_t)L * 589824 + (size_t)(oc * 256 + ic) * 9;
        int q = ic >> 6, kh = (ic >> 5) & 1, s8 = (ic >> 3) & 3, e = ic & 7;
        ushort_t* d = TowerWtAll + (size_t)g * 589824 + (((q * 2 + kh) * 4 + s8) * 2048) + oc * 8 + e;
        #pragma unroll
        for (int t = 0; t < 9; t++) d[t * 65536] = f2bf(s[t]);
    } else if (bid < 2176) {                // cls head: 32768 ids
        int id = (bid - 2048) * 256 + threadIdx.x;
        int oc = id >> 8, ic = id & 255;
        int q = ic >> 6, kh = (ic >> 5) & 1, s8 = (ic >> 3) & 3, e = ic & 7;
        ushort_t* d = WtCls + (((q * 2 + kh) * 4 + s8) * 1024) + oc * 8 + e;
        if (oc < 80) {
            const float* s = cls_out_w + (size_t)(oc * 256 + ic) * 9;
            #pragma unroll
            for (int t = 0; t < 9; t++) d[t * 32768] = f2bf(s[t]);
        } else {
            #pragma unroll
            for (int t = 0; t < 9; t++) d[t * 32768] = 0;
        }
    } else {                                // reg head: 32768 ids (+ stats zero)
        int id = (bid - 2176) * 256 + threadIdx.x;
        if (id < 5120) Stats[id] = 0.f;     // 20480 B of stats
        int oc = id >> 8, ic = id & 255;
        int q = ic >> 6, kh = (ic >> 5) & 1, s8 = (ic >> 3) & 3, e = ic & 7;
        ushort_t* d = WtReg + (((q * 2 + kh) * 4 + s8) * 1024) + oc * 8 + e;
        if (oc < 26) {
            const float* s; int c;
            if (oc < 4)       { s = bbox_w;  c = oc; }
            else if (oc < 5)  { s = ctr_w;   c = 0; }
            else if (oc < 8)  { s = dim_w;   c = oc - 5; }
            else if (oc < 9)  { s = ori_w;   c = 0; }
            else if (oc < 25) { s = kp_w;    c = oc - 9; }
            else              { s = depth_w; c = 0; }
            const float* sp = s + (size_t)(c * 256 + ic) * 9;
            #pragma unroll
            for (int t = 0; t < 9; t++) d[t * 32768] = f2bf(sp[t]);
        } else {
            #pragma unroll
            for (int t = 0; t < 9; t++) d[t * 32768] = 0;
        }
        if (id < 26) {
            const float* b; int c;
            if (id < 4)       { b = bbox_b;  c = id; }
            else if (id < 5)  { b = ctr_b;   c = 0; }
            else if (id < 8)  { b = dim_b;   c = id - 5; }
            else if (id < 9)  { b = ori_b;   c = 0; }
            else if (id < 25) { b = kp_b;    c = id - 9; }
            else              { b = depth_b; c = 0; }
            RegBias[id] = b[c];
        }
    }
}

// ================= pack all levels (f32 NCHW -> padded bf16 NHWC) + border zeroing =================
__global__ __launch_bounds__(256) void packF_k(
    const float* f0, const float* f1, const float* f2,
    const float* f3, const float* f4, ushort_t* __restrict__ S,
    ushort_t* __restrict__ pb1, ushort_t* __restrict__ pb2, ushort_t* __restrict__ pb3)
{
    int bid = blockIdx.x;
    if (bid >= 2552) {                      // pad path: zero borders of 4 buffers (1000 blocks)
        int u = (bid - 2552) * 256 + threadIdx.x;     // 256000 total
        if (u >= 256000) return;
        int chunk = u & 31; u >>= 5;
        int buf = u & 3; u >>= 2;
        int n = (u >= 1000) ? 1 : 0; int pidx = u - n * 1000;
        int l = 0;
        #pragma unroll
        for (int i = 1; i < 5; i++) if (pidx >= F_PC[i]) l = i;
        int q = pidx - F_PC[l];
        int W = F_W[l], H = F_H[l], Wp = W + 2;
        int py, px;
        if (q < Wp) { py = 0; px = q; }
        else if (q < 2 * Wp) { py = H + 1; px = q - Wp; }
        else { int q2 = q - 2 * Wp; py = 1 + (q2 >> 1); px = (q2 & 1) ? (Wp - 1) : 0; }
        ushort_t* base = S;
        if (buf == 1) base = pb1; else if (buf == 2) base = pb2; else if (buf == 3) base = pb3;
        *(uint4*)(base + ((size_t)n * PTOT + F_PB[l] + py * Wp + px) * 256 + chunk * 8) = uint4{0u,0u,0u,0u};
        return;
    }
    __shared__ ushort_t tile[64][65];
    const int PCUM[6] = {0, 1904, 2384, 2504, 2536, 2552};
    const int PT[5]   = {238, 60, 15, 4, 2};
    int l = 0;
    #pragma unroll
    for (int i = 1; i < 5; i++) if (bid >= PCUM[i]) l = i;
    int r = bid - PCUM[l];
    int per_n = PT[l] * 4;
    int n = (r >= per_n) ? 1 : 0; r -= n * per_n;
    int pb = r >> 2, cb = r & 3;
    const float* fs = f0;
    if (l == 1) fs = f1; else if (l == 2) fs = f2; else if (l == 3) fs = f3; else if (l == 4) fs = f4;
    int HW = F_HW[l], W = F_W[l], Wp = W + 2;
    int p0 = pb * 64, c0 = cb * 64;
    int t = threadIdx.x;
    bool full = (p0 + 64 <= HW);
    if (full && l <= 1) {
        #pragma unroll
        for (int i = 0; i < 4; i++) {
            int idx = i * 256 + t; int cl = idx >> 4, pw = idx & 15;
            const float* rp = fs + (size_t)(n * 256 + c0 + cl) * HW + p0 + pw * 4;
            float4 v = *(const float4*)rp;
            tile[cl][pw * 4 + 0] = f2bf(v.x);
            tile[cl][pw * 4 + 1] = f2bf(v.y);
            tile[cl][pw * 4 + 2] = f2bf(v.z);
            tile[cl][pw * 4 + 3] = f2bf(v.w);
        }
    } else if (full && (l == 2 || l == 4)) {
        #pragma unroll
        for (int i = 0; i < 8; i++) {
            int idx = i * 256 + t; int cl = idx >> 5, pw = idx & 31;
            const float* rp = fs + (size_t)(n * 256 + c0 + cl) * HW + p0 + pw * 2;
            float2 v = *(const float2*)rp;
            tile[cl][pw * 2 + 0] = f2bf(v.x);
            tile[cl][pw * 2 + 1] = f2bf(v.y);
        }
    } else {
        #pragma unroll
        for (int i = 0; i < 16; i++) {
            int idx = i * 256 + t; int cl = idx >> 6, pl = idx & 63;
            int p = p0 + pl; ushort_t v = 0;
            if (p < HW) v = f2bf(fs[(size_t)(n * 256 + c0 + cl) * HW + p]);
            tile[cl][pl] = v;
        }
    }
    __syncthreads();
    ushort_t* ob = S + ((size_t)n * PTOT + F_PB[l]) * 256;
    #pragma unroll
    for (int i = 0; i < 16; i++) {
        int idx = i * 256 + t; int pl = idx >> 6, cl = idx & 63;
        int p = p0 + pl;
        if (p < HW) {
            int y = p / W, x = p - y * W;
            ob[((y + 1) * Wp + (x + 1)) * 256 + c0 + cl] = tile[cl][pl];
        }
    }
}

// ================= tower conv: BK=64, K-split pairs, A via LDS, B direct global->reg PIPELINED ====
// bg(it+1) loads issued at END of body it (after MFMAs consume bg(it) -> same regs, no extra
// live range). Top-of-loop wait = vmcnt(4): drains stageA(it) (oldest 2), leaves bg(it) (newest 4)
// in flight with a full barrier+stage+af-read window before the compiler's wait at first MFMA use.
__global__ __launch_bounds__(512, 4) void convT_k(
    const ushort_t* __restrict__ srcC, const ushort_t* __restrict__ srcR,
    ushort_t* __restrict__ dstC, ushort_t* __restrict__ dstR,
    const ushort_t* __restrict__ wtAll,
    const float* __restrict__ biasC, const float* __restrict__ biasR,
    float* __restrict__ stats, int L)
{
    __shared__ __align__(16) ushort_t SH[32768];   // A: [b*8192 + kh*4096 + row*32 + c*8]; merge reuses all

    int gid = blockIdx.x;                       // 0..1279
    int xcd = gid & 7, idx = gid >> 3;          // idx 0..159
    int bid = xcd * 40 + (idx >> 2);            // tile id 0..319 (span-local to XCD)
    int oc0 = (idx & 1) * 128;
    int tw = (idx >> 1) & 1;

    const ushort_t* src = tw ? srcR : srcC;
    ushort_t* dst = tw ? dstR : dstC;
    const ushort_t* wt = wtAll + (size_t)(tw * 4 + L) * 589824;
    const float* bias = (tw ? biasR : biasC) + L * 256;

    int l = 0;
    #pragma unroll
    for (int i = 1; i < 5; i++) if (bid >= F_TC[i]) l = i;
    int r = bid - F_TC[l];
    int tl = F_TL[l];
    int n = (r >= tl) ? 1 : 0; int tile = r - n * tl;
    int W = F_W[l], HW = F_HW[l], Wp = W + 2;
    int px0 = tile * 128;
    const ushort_t* sbase = src + ((size_t)n * PTOT + F_PB[l]) * 256;
    ushort_t* obase = dst + ((size_t)n * PTOT + F_PB[l]) * 256;

    int tid = threadIdx.x, wv = tid >> 6, ln = tid & 63;   // wv 0..7
    int wr = (wv >> 1) & 1, wc = wv & 1, kh = wv >> 2;     // 2M x 2N x 2K-halves

    int aoff;
    {
        int rloc = wv * 16 + (ln >> 2);
        int p = px0 + rloc; if (p > HW - 1) p = HW - 1;
        int y = p / W, x = p - y * W;
        int c = ((ln & 3) - (rloc >> 1)) & 3;       // global sub-chunk for this LDS slot
        aoff = ((y + 1) * Wp + (x + 1)) * 256 + c * 8;
    }
    int fragoff = (ln >> 4) * 2048;

    auto stageA = [&](int it, int b) {
        int tp = it >> 2, q = it & 3;
        int ky = tp / 3, kx = tp - ky * 3;
        int tapo = ((ky - 1) * Wp + (kx - 1)) * 256 + (q << 6);
        gld16(sbase + aoff + tapo,      &SH[b * 8192 + wv * 512]);
        gld16(sbase + aoff + tapo + 32, &SH[b * 8192 + 4096 + wv * 512]);
    };
    auto ldB = [&](int it, bf16x8* bg) {
        int tp = it >> 2, q = it & 3;
        const ushort_t* wB = wt + (size_t)(((tp * 4 + q) * 2 + kh) * 4) * 2048 + fragoff;
        #pragma unroll
        for (int ni = 0; ni < 4; ni++)
            bg[ni] = *(const bf16x8*)&wB[(oc0 + wc * 64 + ni * 16 + (ln & 15)) * 8];
    };

    f32x4 acc[4][4];
    #pragma unroll
    for (int mi = 0; mi < 4; mi++)
        #pragma unroll
        for (int ni = 0; ni < 4; ni++) acc[mi][ni] = f32x4{0.f, 0.f, 0.f, 0.f};

    bf16x8 bg[4];
    stageA(0, 0);                              // oldest in flight
    asm volatile("" ::: "memory");
    ldB(0, bg);                                // newest in flight

    #pragma unroll 2
    for (int it = 0; it < 36; ++it) {
        // drain own A-stage (oldest 2 of 6); keep bg (newest 4) in flight across the barrier
        asm volatile("s_waitcnt vmcnt(4) lgkmcnt(0)\n\ts_barrier" ::: "memory");
        if (it + 1 < 36) stageA(it + 1, (it + 1) & 1);
        asm volatile("" ::: "memory");         // pin vmem issue order: stage before next ldB
        int b = it & 1;
        bf16x8 af[4];
        #pragma unroll
        for (int mi = 0; mi < 4; mi++) {
            int rA = wr * 64 + mi * 16 + (ln & 15);
            int ch = ((ln >> 4) + (rA >> 1)) & 3;
            af[mi] = *(const bf16x8*)&SH[b * 8192 + kh * 4096 + rA * 32 + ch * 8];
        }
        __builtin_amdgcn_s_setprio(1);
        #pragma unroll
        for (int mi = 0; mi < 4; mi++)
            #pragma unroll
            for (int ni = 0; ni < 4; ni++)
                acc[mi][ni] = __builtin_amdgcn_mfma_f32_16x16x32_bf16(af[mi], bg[ni], acc[mi][ni], 0, 0, 0);
        __builtin_amdgcn_s_setprio(0);
        if (it + 1 < 36) ldB(it + 1, bg);      // overwrite bg AFTER its consumers (WAR keeps order)
    }

    // ---- K-split merge: pair (wv, wv^4). STATIC indices only (rule #20). ----
    __syncthreads();
    f32x4* F4 = (f32x4*)SH;
    int prt = wv ^ 4;
    if (kh == 0) {
        #pragma unroll
        for (int mi = 0; mi < 4; mi++) {
            F4[wv * 512 + ln * 8 + ((mi * 2 + 0) ^ (ln & 7))] = acc[mi][2];
            F4[wv * 512 + ln * 8 + ((mi * 2 + 1) ^ (ln & 7))] = acc[mi][3];
        }
    } else {
        #pragma unroll
        for (int mi = 0; mi < 4; mi++) {
            F4[wv * 512 + ln * 8 + ((mi * 2 + 0) ^ (ln & 7))] = acc[mi][0];
            F4[wv * 512 + ln * 8 + ((mi * 2 + 1) ^ (ln & 7))] = acc[mi][1];
        }
    }
    __syncthreads();
    f32x4 eacc[4][2];
    if (kh == 0) {
        #pragma unroll
        for (int mi = 0; mi < 4; mi++) {
            eacc[mi][0] = acc[mi][0] + F4[prt * 512 + ln * 8 + ((mi * 2 + 0) ^ (ln & 7))];
            eacc[mi][1] = acc[mi][1] + F4[prt * 512 + ln * 8 + ((mi * 2 + 1) ^ (ln & 7))];
        }
    } else {
        #pragma unroll
        for (int mi = 0; mi < 4; mi++) {
            eacc[mi][0] = acc[mi][2] + F4[prt * 512 + ln * 8 + ((mi * 2 + 0) ^ (ln & 7))];
            eacc[mi][1] = acc[mi][3] + F4[prt * 512 + ln * 8 + ((mi * 2 + 1) ^ (ln & 7))];
        }
    }

    // epilogue: this wave finalizes ni = kh*2 + {0,1}
    #pragma unroll
    for (int h = 0; h < 2; h++) {
        int oc = oc0 + wc * 64 + (kh * 2 + h) * 16 + (ln & 15);
        float bv = bias[oc];
        float s = 0.f, q = 0.f;
        #pragma unroll
        for (int mi = 0; mi < 4; mi++) {
            int pb = px0 + wr * 64 + mi * 16 + ((ln >> 4) << 2);
            if (pb < HW) {
                int y = pb / W, x = pb - y * W;
                #pragma unroll
                for (int rr2 = 0; rr2 < 4; rr2++) {
                    int p = pb + rr2;
                    if (p < HW) {
                        float v = eacc[mi][h][rr2] + bv;
                        obase[((y + 1) * Wp + (x + 1)) * 256 + oc] = f2bf(v);
                        s += v; q += v * v;
                    }
                    x++; if (x == W) { x = 0; y++; }
                }
            }
        }
        s += __shfl_xor(s, 16, 64); q += __shfl_xor(q, 16, 64);
        s += __shfl_xor(s, 32, 64); q += __shfl_xor(q, 32, 64);
        s += __shfl_xor(s, 1, 64);  q += __shfl_xor(q, 1, 64);
        s += __shfl_xor(s, 2, 64);  q += __shfl_xor(q, 2, 64);
        s += __shfl_xor(s, 4, 64);  q += __shfl_xor(q, 4, 64);
        if (ln == 0 || ln == 8) {
            int g = (oc0 + wc * 64 + (kh * 2 + h) * 16 + (ln & 8)) >> 3;
            float* st = stats + (size_t)((tw * 4 + L) * 5 + l) * 128 + (n * 32 + g) * 2;
            atomicAdd(st, s); atomicAdd(st + 1, q);
        }
    }
}

// ================= head conv: BK=64, K-split pairs, B direct->reg pipelined; mode-1 skips ==========
__global__ __launch_bounds__(512, 4) void convH_k(
    const ushort_t* __restrict__ srcC, const ushort_t* __restrict__ srcR,
    const ushort_t* __restrict__ wtC, const ushort_t* __restrict__ wtR,
    const float* __restrict__ biasC, const float* __restrict__ biasR,
    float* __restrict__ outF)
{
    __shared__ __align__(16) ushort_t SH[32768];

    int gid = blockIdx.x;                      // 0..639
    int xcd = gid & 7, idx = gid >> 3;         // idx 0..79
    int bid = xcd * 40 + (idx >> 1);           // tile 0..319
    int mode = idx & 1;

    const ushort_t* src = mode ? srcR : srcC;
    const ushort_t* wt  = mode ? wtR  : wtC;
    const float* bias   = mode ? biasR : biasC;

    int l = 0;
    #pragma unroll
    for (int i = 1; i < 5; i++) if (bid >= F_TC[i]) l = i;
    int r = bid - F_TC[l];
    int tl = F_TL[l];
    int n = (r >= tl) ? 1 : 0; int tile = r - n * tl;
    int W = F_W[l], HW = F_HW[l], Wp = W + 2;
    int px0 = tile * 128;
    const ushort_t* sbase = src + ((size_t)n * PTOT + F_PB[l]) * 256;

    int tid = threadIdx.x, wv = tid >> 6, ln = tid & 63;
    int wr = (wv >> 1) & 1, wc = wv & 1, kh = wv >> 2;
    bool active = (mode == 0) || (wc == 0);   // mode1: only oc<26 valid (all in wc==0)

    int aoff;
    {
        int rloc = wv * 16 + (ln >> 2);
        int p = px0 + rloc; if (p > HW - 1) p = HW - 1;
        int y = p / W, x = p - y * W;
        int c = ((ln & 3) - (rloc >> 1)) & 3;
        aoff = ((y + 1) * Wp + (x + 1)) * 256 + c * 8;
    }
    int fragoff = (ln >> 4) * 1024;

    auto stageA = [&](int it, int b) {
        int tp = it >> 2, q = it & 3;
        int ky = tp / 3, kx = tp - ky * 3;
        int tapo = ((ky - 1) * Wp + (kx - 1)) * 256 + (q << 6);
        gld16(sbase + aoff + tapo,      &SH[b * 8192 + wv * 512]);
        gld16(sbase + aoff + tapo + 32, &SH[b * 8192 + 4096 + wv * 512]);
    };
    auto ldB = [&](int it, bf16x8* bg) {
        int tp = it >> 2, q = it & 3;
        const ushort_t* wB = wt + (size_t)(((tp * 4 + q) * 2 + kh) * 4) * 1024 + fragoff;
        #pragma unroll
        for (int ni = 0; ni < 4; ni++)
            bg[ni] = *(const bf16x8*)&wB[(wc * 64 + ni * 16 + (ln & 15)) * 8];
    };

    f32x4 acc[4][4];
    #pragma unroll
    for (int mi = 0; mi < 4; mi++)
        #pragma unroll
        for (int ni = 0; ni < 4; ni++) acc[mi][ni] = f32x4{0.f, 0.f, 0.f, 0.f};

    bf16x8 bg[4];
    stageA(0, 0);
    asm volatile("" ::: "memory");
    if (active) ldB(0, bg);

    #pragma unroll 2
    for (int it = 0; it < 36; ++it) {
        // active waves keep their 4 bg loads in flight; inactive waves have only the 2 stage
        // loads outstanding and must drain them fully before the barrier.
        if (active) {
            asm volatile("s_waitcnt vmcnt(4) lgkmcnt(0)\n\ts_barrier" ::: "memory");
        } else {
            asm volatile("s_waitcnt vmcnt(0) lgkmcnt(0)\n\ts_barrier" ::: "memory");
        }
        if (it + 1 < 36) stageA(it + 1, (it + 1) & 1);
        asm volatile("" ::: "memory");
        int b = it & 1;
        if (active) {
            bf16x8 af[4];
            #pragma unroll
            for (int mi = 0; mi < 4; mi++) {
                int rA = wr * 64 + mi * 16 + (ln & 15);
                int ch = ((ln >> 4) + (rA >> 1)) & 3;
                af[mi] = *(const bf16x8*)&SH[b * 8192 + kh * 4096 + rA * 32 + ch * 8];
            }
            __builtin_amdgcn_s_setprio(1);
            #pragma unroll
            for (int mi = 0; mi < 4; mi++)
                #pragma unroll
                for (int ni = 0; ni < 4; ni++)
                    acc[mi][ni] = __builtin_amdgcn_mfma_f32_16x16x32_bf16(af[mi], bg[ni], acc[mi][ni], 0, 0, 0);
            __builtin_amdgcn_s_setprio(0);
            if (it + 1 < 36) ldB(it + 1, bg);
        }
    }

    __syncthreads();
    f32x4* F4 = (f32x4*)SH;
    int prt = wv ^ 4;
    if (active) {
        if (kh == 0) {
            #pragma unroll
            for (int mi = 0; mi < 4; mi++) {
                F4[wv * 512 + ln * 8 + ((mi * 2 + 0) ^ (ln & 7))] = acc[mi][2];
                F4[wv * 512 + ln * 8 + ((mi * 2 + 1) ^ (ln & 7))] = acc[mi][3];
            }
        } else {
            #pragma unroll
            for (int mi = 0; mi < 4; mi++) {
                F4[wv * 512 + ln * 8 + ((mi * 2 + 0) ^ (ln & 7))] = acc[mi][0];
                F4[wv * 512 + ln * 8 + ((mi * 2 + 1) ^ (ln & 7))] = acc[mi][1];
            }
        }
    }
    __syncthreads();
    f32x4 eacc[4][2];
    if (kh == 0) {
        #pragma unroll
        for (int mi = 0; mi < 4; mi++) {
            eacc[mi][0] = acc[mi][0] + F4[prt * 512 + ln * 8 + ((mi * 2 + 0) ^ (ln & 7))];
            eacc[mi][1] = acc[mi][1] + F4[prt * 512 + ln * 8 + ((mi * 2 + 1) ^ (ln & 7))];
        }
    } else {
        #pragma unroll
        for (int mi = 0; mi < 4; mi++) {
            eacc[mi][0] = acc[mi][2] + F4[prt * 512 + ln * 8 + ((mi * 2 + 0) ^ (ln & 7))];
            eacc[mi][1] = acc[mi][3] + F4[prt * 512 + ln * 8 + ((mi * 2 + 1) ^ (ln & 7))];
        }
    }

    #pragma unroll
    for (int h = 0; h < 2; h++) {
        int oc = wc * 64 + (kh * 2 + h) * 16 + (ln & 15);
        bool valid = mode ? (oc < 26) : (oc < 80);
        if (valid) {
            float bv = bias[oc];
            int rb = 0, rm = 80, rc = oc; bool rl = false;
            if (mode) { rb = d_RB[oc]; rm = d_RM[oc]; rc = d_RC[oc]; rl = (oc < 4); }
            #pragma unroll
            for (int mi = 0; mi < 4; mi++) {
                int pb = px0 + wr * 64 + mi * 16 + ((ln >> 4) << 2);
                #pragma unroll
                for (int rr2 = 0; rr2 < 4; rr2++) {
                    int p = pb + rr2;
                    if (p < HW) {
                        float v = eacc[mi][h][rr2] + bv;
                        if (rl) v = fmaxf(v, 0.f);
                        int pg = n * TOTAL_HW + F_LOFF[l] + p;
                        outF[rb + (size_t)pg * rm + rc] = v;
                    }
                }
            }
        }
    }
}

// ================= merged GN finalize+affine+relu (both towers, all levels) =================
__global__ __launch_bounds__(256) void normF_k(
    ushort_t* __restrict__ bufC, ushort_t* __restrict__ bufR,
    const float* __restrict__ stats,
    const float* __restrict__ gwC, const float* __restrict__ gwR,
    const float* __restrict__ gbC, const float* __restrict__ gbR, int L)
{
    int u = blockIdx.x * 256 + threadIdx.x;
    if (u >= 2594176) return;                 // 2tw * 2n * 20267 * 32
    int tw = (u >= 1297088) ? 1 : 0; u -= tw * 1297088;
    int n = (u >= 648544) ? 1 : 0; u -= n * 648544;
    int cp = u >> 5, g = u & 31;
    int l = 0;
    #pragma unroll
    for (int i = 1; i < 5; i++) if (cp >= F_LOFF[i]) l = i;
    int p = cp - F_LOFF[l];
    int W = F_W[l], HW = F_HW[l];
    int y = p / W, x = p - y * W;
    const float* st = stats + (size_t)((tw * 4 + L) * 5 + l) * 128 + (n * 32 + g) * 2;
    float cnt = 8.0f * (float)HW;
    float mean = st[0] / cnt;
    float var = st[1] / cnt - mean * mean;
    float inv = rsqrtf(fmaxf(var, 0.f) + 1e-5f);
    const float* gw = (tw ? gwR : gwC) + L * 256 + g * 8;
    const float* gb = (tw ? gbR : gbC) + L * 256 + g * 8;
    ushort_t* buf = tw ? bufR : bufC;
    ushort_t* ptr = buf + (((size_t)n * PTOT + F_PB[l]) + (y + 1) * (W + 2) + (x + 1)) * 256 + g * 8;
    uint4 din = *(const uint4*)ptr;
    uint4 dout;
    const ushort_t* xi = (const ushort_t*)&din;
    ushort_t* oi = (ushort_t*)&dout;
    #pragma unroll
    for (int i = 0; i < 8; i++) {
        float v = (bf2f(xi[i]) - mean) * inv * gw[i] + gb[i];
        oi[i] = f2bf(fmaxf(v, 0.f));
    }
    *(uint4*)ptr = dout;
}

// ---------------- ws layout (bytes) ----------------
// Stats 0..20,480 | RegBias 20,480..20,608 | TowerWtAll 20,608..9,457,792
// WtCls 9,457,792..10,047,616 | WtReg 10,047,616..10,637,440
// S 10,637,440 | Ac 32,414,848 | Ar 54,192,256 | Br 75,969,664 | end 97,747,072

extern "C" void kernel_launch(void* const* d_in, const int* in_sizes, int n_in,
                              void* d_out, int out_size, void* d_ws, size_t ws_size,
                              hipStream_t stream) {
    const float* feats[5] = {(const float*)d_in[0], (const float*)d_in[1],
                             (const float*)d_in[2], (const float*)d_in[3],
                             (const float*)d_in[4]};
    const float* cls_conv_w = (const float*)d_in[5];
    const float* cls_conv_b = (const float*)d_in[6];
    const float* cls_gn_w   = (const float*)d_in[7];
    const float* cls_gn_b   = (const float*)d_in[8];
    const float* cls_out_w  = (const float*)d_in[9];
    const float* cls_out_b  = (const float*)d_in[10];
    const float* reg_conv_w = (const float*)d_in[11];
    const float* reg_conv_b = (const float*)d_in[12];
    const float* reg_gn_w   = (const float*)d_in[13];
    const float* reg_gn_b   = (const float*)d_in[14];

    char* wsb = (char*)d_ws;
    float* Stats     = (float*)wsb;
    float* RegBias   = (float*)(wsb + 20480);
    ushort_t* TowerWtAll = (ushort_t*)(wsb + 20608);
    ushort_t* WtCls  = (ushort_t*)(wsb + 9457792);
    ushort_t* WtReg  = (ushort_t*)(wsb + 10047616);
    ushort_t* S  = (ushort_t*)(wsb + 10637440);
    ushort_t* Ac = (ushort_t*)(wsb + 32414848);
    ushort_t* Ar = (ushort_t*)(wsb + 54192256);
    ushort_t* Br = (ushort_t*)(wsb + 75969664);
    float* outf  = (float*)d_out;

    wprep_k<<<2304, 256, 0, stream>>>(
        cls_conv_w, reg_conv_w, cls_out_w,
        (const float*)d_in[15], (const float*)d_in[17], (const float*)d_in[19],
        (const float*)d_in[21], (const float*)d_in[23], (const float*)d_in[25],
        (const float*)d_in[16], (const float*)d_in[18], (const float*)d_in[20],
        (const float*)d_in[22], (const float*)d_in[24], (const float*)d_in[26],
        TowerWtAll, WtCls, WtReg, RegBias, Stats);

    packF_k<<<3552, 256, 0, stream>>>(feats[0], feats[1], feats[2], feats[3], feats[4],
                                      S, Ac, Ar, Br);

    ushort_t* sc[4] = {S,  Ac, S,  Ac};
    ushort_t* dc[4] = {Ac, S,  Ac, S };
    ushort_t* sr[4] = {S,  Ar, Br, Ar};
    ushort_t* dr[4] = {Ar, Br, Ar, Br};
    for (int L = 0; L < 4; L++) {
        convT_k<<<1280, 512, 0, stream>>>(
            sc[L], sr[L], dc[L], dr[L], TowerWtAll, cls_conv_b, reg_conv_b, Stats, L);
        normF_k<<<10134, 256, 0, stream>>>(
            dc[L], dr[L], Stats, cls_gn_w, reg_gn_w, cls_gn_b, reg_gn_b, L);
    }
    convH_k<<<640, 512, 0, stream>>>(S, Br, WtCls, WtReg, cls_out_b, RegBias, outf);
}